// Round 1
// baseline (144.560 us; speedup 1.0000x reference)
//
#include <hip/hip_runtime.h>

// Elementwise 16-step SNN scan.
// Per element:
//   v = |x|; z = 0; acc = 0
//   for t in 0..15:
//     v   = v - z*h[t]
//     z   = ((v - T[t]) / (|v|+1) > 0)  ==  (v > T[t])   [denominator > 0]
//     acc = acc + z*d[t]
//   out = acc * sign(x)
// All arithmetic matches the fp32 reference bit-exactly (z in {0,1} makes
// every product exact; fmaf then performs the same single rounding as ref).

__device__ __forceinline__ float snn_elem(float xe,
                                          const float* __restrict__ hh,
                                          const float* __restrict__ dd,
                                          const float* __restrict__ TT) {
    float v = fabsf(xe);
    // t = 0 peeled: z starts at 0, so v is unchanged.
    float z   = (v > TT[0]) ? 1.0f : 0.0f;
    float acc = z * dd[0];
#pragma unroll
    for (int t = 1; t < 16; ++t) {
        v   = fmaf(-z, hh[t], v);           // v - z*h[t], exact product
        z   = (v > TT[t]) ? 1.0f : 0.0f;    // sign of (v-T)/(|v|+1)
        acc = fmaf(z, dd[t], acc);          // acc + z*d[t], exact product
    }
    float s = (xe > 0.0f) ? 1.0f : ((xe < 0.0f) ? -1.0f : 0.0f);
    return acc * s;
}

__global__ __launch_bounds__(256) void snn_scan_kernel(
    const float* __restrict__ x,
    const float* __restrict__ h,
    const float* __restrict__ d,
    const float* __restrict__ T,
    float* __restrict__ out,
    int n4, int n) {
    // Constants: constant indices off wave-uniform pointers -> scalar loads.
    float hh[16], dd[16], TT[16];
#pragma unroll
    for (int t = 0; t < 16; ++t) {
        hh[t] = h[t];
        dd[t] = d[t];
        TT[t] = T[t];
    }

    const int stride = gridDim.x * blockDim.x;
    const float4* __restrict__ x4 = reinterpret_cast<const float4*>(x);
    float4* __restrict__ o4       = reinterpret_cast<float4*>(out);

    for (int i = blockIdx.x * blockDim.x + threadIdx.x; i < n4; i += stride) {
        float4 xv = x4[i];
        float4 ov;
        ov.x = snn_elem(xv.x, hh, dd, TT);
        ov.y = snn_elem(xv.y, hh, dd, TT);
        ov.z = snn_elem(xv.z, hh, dd, TT);
        ov.w = snn_elem(xv.w, hh, dd, TT);
        o4[i] = ov;
    }

    // Scalar tail (n not divisible by 4) — empty for the bench shape.
    for (int i = n4 * 4 + blockIdx.x * blockDim.x + threadIdx.x; i < n;
         i += stride) {
        out[i] = snn_elem(x[i], hh, dd, TT);
    }
}

extern "C" void kernel_launch(void* const* d_in, const int* in_sizes, int n_in,
                              void* d_out, int out_size, void* d_ws, size_t ws_size,
                              hipStream_t stream) {
    const float* x = (const float*)d_in[0];
    const float* h = (const float*)d_in[1];
    const float* d = (const float*)d_in[2];
    const float* T = (const float*)d_in[3];
    float* out     = (float*)d_out;

    const int n  = in_sizes[0];
    const int n4 = n / 4;

    const int block = 256;
    int grid = 2048;  // 256 CU x 8 blocks/CU; grid-stride covers the rest
    const int needed = (n4 + block - 1) / block;
    if (grid > needed) grid = needed > 0 ? needed : 1;

    snn_scan_kernel<<<grid, block, 0, stream>>>(x, h, d, T, out, n4, n);
}